// Round 18
// baseline (158.685 us; speedup 1.0000x reference)
//
#include <hip/hip_runtime.h>
#include <math.h>

#define DEV __device__ __forceinline__
DEV float leakyf(float v) { return v >= 0.f ? v : 0.01f * v; }
DEV int rfl(int v) { return __builtin_amdgcn_readfirstlane(v); }

struct F4 { float x, y, z, w; };   // natural align 4: legal on any float*

// ---- ws layout (float offsets) ----
#define OFF_H1P  1081600u    // h1 [64][8][66][66]           2230272
#define OFF_H2P  3311872u    // h2 [64][16][34][34]          1183744
#define OFF_H3   4495616u    // h3 [64][16][32][32]          1048576
#define OFF_D1P  5544192u    // d1 [64][16][34][34]          1183744
#define OFF_D2P  6727936u    // d2 [64][8][66][66]           2230272
#define OFF_IDX  8958208u    // 65536 int32
#define OFF_U    9023744u    // 73728 [k512][tap9][co16]
#define OFF_C2   9097472u    // 512
#define OFF_W4T  9097984u    // 1024 [ci16][d64]
#define OFF_LOSS 9099008u    // 1 (+pad)
#define OFF_DWT  9100032u    // 9216 [ci64][tap9*16+co16]

// ---------- halo zeroing helper ----------
DEV void halo_store(float* base, int plane, int r, int W, int H, long psz)
{
    int row, col;
    if (r < W)          { row = 0;     col = r; }
    else if (r < 2 * W) { row = H - 1; col = r - W; }
    else { int r2 = r - 2 * W; row = 1 + (r2 >> 1); col = (r2 & 1) ? W - 1 : 0; }
    base[plane * psz + row * W + col] = 0.f;
}

// ---------- setup: halos + W4T + C2 + DWT + LOSS zero ----------
__global__ void setup_k(const float* __restrict__ ew4, const float* __restrict__ dw1,
                        const float* __restrict__ cb, float* __restrict__ ws)
{
    int id = blockIdx.x * 256 + threadIdx.x;       // 547456 ids
    if (id < 133120) {                             // H1P halos: 512 x 260
        halo_store(ws + OFF_H1P, id / 260, id % 260, 66, 66, 4356);
    } else if (id < 268288) {                      // H2P halos: 1024 x 132
        int i = id - 133120;
        halo_store(ws + OFF_H2P, i / 132, i % 132, 34, 34, 1156);
    } else if (id < 403456) {                      // D1P halos
        int i = id - 268288;
        halo_store(ws + OFF_D1P, i / 132, i % 132, 34, 34, 1156);
    } else if (id < 536576) {                      // D2P halos: 512 x 260
        int i = id - 403456;
        halo_store(ws + OFF_D2P, i / 260, i % 260, 66, 66, 4356);
    } else if (id < 537600) {                      // W4T: [ci*64+d] = ew4[d][ci]
        int i = id - 536576;
        int d = i & 63, ci = i >> 6;
        ws[OFF_W4T + i] = ew4[d * 16 + ci];
    } else if (id < 538112) {                      // C2
        int k = id - 537600;
        float s = 0.f;
        #pragma unroll
        for (int d = 0; d < 64; ++d) { float v = cb[k * 64 + d]; s = fmaf(v, v, s); }
        ws[OFF_C2 + k] = s;
    } else if (id == 538112) {
        ws[OFF_LOSS] = 0.f;
    } else if (id >= 538240 && id < 547456) {      // DWT: [ci*144+tap*16+co]
        int i = id - 538240;
        int co = i & 15, tap = (i >> 4) % 9, ci = i / 144;
        ws[OFF_DWT + i] = dw1[(co * 64 + ci) * 9 + tap];
    }
}

// U[k][tap][co] = sum_ci dwT[ci][tap*16+co] * cb[k][ci]   (coalesced)
__global__ void uprep_k(const float* __restrict__ dwT, const float* __restrict__ cb,
                        float* __restrict__ U)
{
    int id = blockIdx.x * 256 + threadIdx.x;   // 73728
    int k = id / 144;
    int r = id - k * 144;
    float s = 0.f;
    #pragma unroll
    for (int ci = 0; ci < 64; ++ci)
        s = fmaf(cb[k * 64 + ci], dwT[ci * 144 + r], s);
    U[id] = s;
}

// ---------- e1: 1->8, K4 S2 P1, reads x directly (bounds-checked) ----------
__global__ __launch_bounds__(256) void e1d_k(const float* __restrict__ x,
                                             const float* __restrict__ ew1,
                                             const float* __restrict__ eb1,
                                             float* __restrict__ h1p)
{
    __shared__ float wl[128];
    int t = threadIdx.x;
    if (t < 128) { int co = t & 7, tap = t >> 3; wl[t] = ew1[co * 16 + tap]; }
    __syncthreads();
    int id = blockIdx.x * 256 + t;                 // 262144
    int px = id & 63, py = (id >> 6) & 63, n = id >> 12;
    float acc[8];
    #pragma unroll
    for (int j = 0; j < 8; ++j) acc[j] = eb1[j];
    const float* ip = x + (n << 14);
    #pragma unroll
    for (int ky = 0; ky < 4; ++ky) {
        int iy = 2 * py - 1 + ky;
        bool vy = iy >= 0 && iy < 128;
        #pragma unroll
        for (int kx = 0; kx < 4; ++kx) {
            int ix = 2 * px - 1 + kx;
            float v = (vy && ix >= 0 && ix < 128) ? ip[(iy << 7) + ix] : 0.f;
            const float* wp = &wl[(ky * 4 + kx) * 8];
            #pragma unroll
            for (int j = 0; j < 8; ++j) acc[j] = fmaf(v, wp[j], acc[j]);
        }
    }
    #pragma unroll
    for (int j = 0; j < 8; ++j)
        h1p[((n * 8 + j) * 66 + py + 1) * 66 + px + 1] = leakyf(acc[j]);
}

// ---------- e2: 8->16, K4 S2 P1, COB4 ----------
__global__ __launch_bounds__(256) void e2p_k(const float* __restrict__ h1p,
                                             const float* __restrict__ ew2,
                                             const float* __restrict__ eb2,
                                             float* __restrict__ h2p)
{
    __shared__ float wl[512];
    int t = threadIdx.x;
    int id = blockIdx.x * 256 + t;                 // 262144
    int x = id & 31, y = (id >> 5) & 31;
    int cg = rfl((id >> 10) & 3), n = id >> 12;
    for (int i = t; i < 512; i += 256) {
        int co = i & 3, r = i >> 2;
        int kx = r & 3, ky = (r >> 2) & 3, ci = r >> 4;
        wl[i] = ew2[((cg * 4 + co) * 8 + ci) * 16 + ky * 4 + kx];
    }
    __syncthreads();
    float acc[4];
    #pragma unroll
    for (int j = 0; j < 4; ++j) acc[j] = eb2[cg * 4 + j];
    #pragma unroll 1
    for (int ci = 0; ci < 8; ++ci) {
        const float* base = h1p + ((n * 8 + ci) * 66 + 2 * y) * 66 + 2 * x;
        #pragma unroll
        for (int ky = 0; ky < 4; ++ky) {
            F4 v = *(const F4*)(base + ky * 66);
            float vv[4] = { v.x, v.y, v.z, v.w };
            #pragma unroll
            for (int kx = 0; kx < 4; ++kx) {
                const float* wp = &wl[((ci * 4 + ky) * 4 + kx) * 4];
                acc[0] = fmaf(vv[kx], wp[0], acc[0]);
                acc[1] = fmaf(vv[kx], wp[1], acc[1]);
                acc[2] = fmaf(vv[kx], wp[2], acc[2]);
                acc[3] = fmaf(vv[kx], wp[3], acc[3]);
            }
        }
    }
    #pragma unroll
    for (int j = 0; j < 4; ++j)
        h2p[((n * 16 + cg * 4 + j) * 34 + y + 1) * 34 + x + 1] = leakyf(acc[j]);
}

// ---------- e3: 16->16, K3 S1 P1, COB4; writes UNPADDED h3 ----------
__global__ __launch_bounds__(256) void e3p_k(const float* __restrict__ h2p,
                                             const float* __restrict__ ew3,
                                             const float* __restrict__ eb3,
                                             float* __restrict__ h3)
{
    __shared__ float wl[576];
    int t = threadIdx.x;
    int id = blockIdx.x * 256 + t;                 // 262144
    int x = id & 31, y = (id >> 5) & 31;
    int cg = rfl((id >> 10) & 3), n = id >> 12;
    for (int i = t; i < 576; i += 256) {
        int co = i & 3, r = i >> 2;
        int kx = r % 3, ky = (r / 3) % 3, ci = r / 9;
        wl[i] = ew3[((cg * 4 + co) * 16 + ci) * 9 + ky * 3 + kx];
    }
    __syncthreads();
    float acc[4];
    #pragma unroll
    for (int j = 0; j < 4; ++j) acc[j] = eb3[cg * 4 + j];
    #pragma unroll 1
    for (int ci = 0; ci < 16; ++ci) {
        const float* base = h2p + ((n * 16 + ci) * 34 + y) * 34 + x;
        #pragma unroll
        for (int ky = 0; ky < 3; ++ky) {
            F4 v = *(const F4*)(base + ky * 34);
            float vv[3] = { v.x, v.y, v.z };
            #pragma unroll
            for (int kx = 0; kx < 3; ++kx) {
                const float* wp = &wl[((ci * 3 + ky) * 3 + kx) * 4];
                acc[0] = fmaf(vv[kx], wp[0], acc[0]);
                acc[1] = fmaf(vv[kx], wp[1], acc[1]);
                acc[2] = fmaf(vv[kx], wp[2], acc[2]);
                acc[3] = fmaf(vv[kx], wp[3], acc[3]);
            }
        }
    }
    #pragma unroll
    for (int j = 0; j < 4; ++j)
        h3[((n * 16 + cg * 4 + j) << 10) + (y << 5) + x] = leakyf(acc[j]);
}

// ---------- fused e4 + VQ (vqn): 384 threads, 192-code panels, 80KB LDS ----
// Same 8x8 tile / d-major geometry as vqh; 12 waves/CU instead of 8.
// Panels: 192,192,128 (tail handled by tc<16). Exact first-min preserved.
__global__ __launch_bounds__(384) void vqn_k(const float* __restrict__ h3,
                                             const float* __restrict__ w4t,
                                             const float* __restrict__ eb4,
                                             const float* __restrict__ cb,
                                             const float* __restrict__ c2,
                                             int* __restrict__ idxOut,
                                             float* __restrict__ lossAcc)
{
    __shared__ float Fs[64 * 128];     // 32 KB [d][row]
    __shared__ float Cs[64 * 192];     // 48 KB [d][code<=192]; aliased for red
    int t = threadIdx.x;
    int row0 = blockIdx.x << 7;
    int n = row0 >> 10;
    int pos0 = row0 & 1023;

    // ---- stage F on first 256 threads (proven pattern) ----
    if (t < 256) {
        int row = t & 127, dh = t >> 7;
        const float* hp = h3 + (n << 14) + pos0 + row;
        float h[16];
        #pragma unroll
        for (int ci = 0; ci < 16; ++ci) h[ci] = hp[ci << 10];
        #pragma unroll
        for (int q = 0; q < 8; ++q) {
            int d0 = dh * 32 + q * 4;
            float a0 = eb4[d0 + 0], a1 = eb4[d0 + 1];
            float a2 = eb4[d0 + 2], a3 = eb4[d0 + 3];
            #pragma unroll
            for (int ci = 0; ci < 16; ++ci) {
                float v = h[ci];
                const float* wp = w4t + (ci << 6) + d0;
                a0 = fmaf(v, wp[0], a0); a1 = fmaf(v, wp[1], a1);
                a2 = fmaf(v, wp[2], a2); a3 = fmaf(v, wp[3], a3);
            }
            Fs[(d0 + 0) * 128 + row] = leakyf(a0);
            Fs[(d0 + 1) * 128 + row] = leakyf(a1);
            Fs[(d0 + 2) * 128 + row] = leakyf(a2);
            Fs[(d0 + 3) * 128 + row] = leakyf(a3);
        }
    }

    int tr = t & 15, tc = t >> 4;      // tc 0..23
    float best[8]; int bk[8];
    #pragma unroll
    for (int i = 0; i < 8; ++i) { best[i] = 3.4e38f; bk[i] = 0; }

    #pragma unroll 1
    for (int p = 0; p < 3; ++p) {
        __syncthreads();               // Fs ready (p=0) / prior Cs reads done
        if (p < 2) {                   // stage 192 codes: code = t>>1, dh = t&1
            int code = t >> 1, dh = t & 1;
            const float* src = cb + (((p * 192) + code) << 6) + dh * 32;
            #pragma unroll
            for (int q = 0; q < 8; ++q) {
                float4 v = *(const float4*)(src + q * 4);
                int d0 = dh * 32 + q * 4;
                Cs[(d0 + 0) * 192 + code] = v.x;
                Cs[(d0 + 1) * 192 + code] = v.y;
                Cs[(d0 + 2) * 192 + code] = v.z;
                Cs[(d0 + 3) * 192 + code] = v.w;
            }
        } else if (t < 256) {          // tail panel: 128 codes
            int code = t >> 1, dh = t & 1;
            const float* src = cb + ((384 + code) << 6) + dh * 32;
            #pragma unroll
            for (int q = 0; q < 8; ++q) {
                float4 v = *(const float4*)(src + q * 4);
                int d0 = dh * 32 + q * 4;
                Cs[(d0 + 0) * 192 + code] = v.x;
                Cs[(d0 + 1) * 192 + code] = v.y;
                Cs[(d0 + 2) * 192 + code] = v.z;
                Cs[(d0 + 3) * 192 + code] = v.w;
            }
        }
        __syncthreads();

        bool active = (p < 2) || (tc < 16);
        if (active) {
            int cOff1 = (p < 2) ? 96 : 64;
            float acc[8][8];
            #pragma unroll
            for (int i = 0; i < 8; ++i)
                #pragma unroll
                for (int j = 0; j < 8; ++j) acc[i][j] = 0.f;

            const float* fp0 = &Fs[tr * 4];
            const float* fp1 = &Fs[64 + tr * 4];
            const float* cp0 = &Cs[tc * 4];
            const float* cp1 = &Cs[cOff1 + tc * 4];
            #pragma unroll 8
            for (int d = 0; d < 64; ++d) {
                float4 f0 = *(const float4*)(fp0 + d * 128);
                float4 f1 = *(const float4*)(fp1 + d * 128);
                float4 c0 = *(const float4*)(cp0 + d * 192);
                float4 c1 = *(const float4*)(cp1 + d * 192);
                float f[8] = { f0.x, f0.y, f0.z, f0.w, f1.x, f1.y, f1.z, f1.w };
                float c[8] = { c0.x, c0.y, c0.z, c0.w, c1.x, c1.y, c1.z, c1.w };
                #pragma unroll
                for (int i = 0; i < 8; ++i)
                    #pragma unroll
                    for (int j = 0; j < 8; ++j)
                        acc[i][j] = fmaf(f[i], c[j], acc[i][j]);
            }
            int kBase = p * 192;
            #pragma unroll
            for (int j = 0; j < 8; ++j) {  // ascending kk within thread
                int kk = kBase + (j < 4 ? tc * 4 + j : cOff1 + tc * 4 + j - 4);
                float hc2 = 0.5f * c2[kk];
                #pragma unroll
                for (int i = 0; i < 8; ++i) {
                    float s = hc2 - acc[i][j];
                    if (s < best[i]) { best[i] = s; bk[i] = kk; }
                }
            }
        }
    }

    __syncthreads();                   // all Cs reads done; alias for reduction
    float* redS = Cs;                  // [row128][25]
    int*   redI = (int*)(Cs + 3328);
    #pragma unroll
    for (int i = 0; i < 8; ++i) {
        int row = (i < 4) ? tr * 4 + i : 64 + tr * 4 + i - 4;
        redS[row * 25 + tc] = best[i];
        redI[row * 25 + tc] = bk[i];
    }
    __syncthreads();
    if (t < 128) {
        int row = t;
        float bs = redS[row * 25]; int bi = redI[row * 25];
        #pragma unroll
        for (int c = 1; c < 24; ++c) {    // (score, idx) lexicographic = first-min
            float s2 = redS[row * 25 + c];
            int   i2 = redI[row * 25 + c];
            if (s2 < bs || (s2 == bs && i2 < bi)) { bs = s2; bi = i2; }
        }
        idxOut[row0 + row] = bi;
        const float* cr = cb + (bi << 6);
        float rs = 0.f;
        #pragma unroll
        for (int d = 0; d < 64; ++d) {
            float e = cr[d] - Fs[d * 128 + row];
            rs = fmaf(e, e, rs);
        }
        #pragma unroll
        for (int off = 32; off; off >>= 1) rs += __shfl_down(rs, off, 64);
        if ((t & 63) == 0) atomicAdd(lossAcc, rs);
    }
}

// ---------- d1 via U-table, writes PADDED D1P; finalizes loss ----------
__global__ __launch_bounds__(256) void d1p_k(const int* __restrict__ idx,
                                             const float* __restrict__ U,
                                             const float* __restrict__ db1,
                                             const float* __restrict__ lossAcc,
                                             float* __restrict__ lossOut,
                                             float* __restrict__ d1p)
{
    int id = blockIdx.x * 256 + threadIdx.x;       // 262144
    if (id == 0) lossOut[0] = 1.25f * lossAcc[0] / 4194304.0f;
    int x = id & 31, y = (id >> 5) & 31;
    int cg = rfl((id >> 10) & 3), n = id >> 12;
    float acc[4];
    #pragma unroll
    for (int j = 0; j < 4; ++j) acc[j] = db1[cg * 4 + j];
    const float4* U4 = (const float4*)U;
    #pragma unroll
    for (int tap = 0; tap < 9; ++tap) {
        int yy = y + tap / 3 - 1, xx = x + tap % 3 - 1;
        if (yy < 0 || yy > 31 || xx < 0 || xx > 31) continue;
        int k = idx[(n << 10) + (yy << 5) + xx];
        float4 u = U4[(k * 9 + tap) * 4 + cg];
        acc[0] += u.x; acc[1] += u.y; acc[2] += u.z; acc[3] += u.w;
    }
    #pragma unroll
    for (int j = 0; j < 4; ++j)
        d1p[((n * 16 + cg * 4 + j) * 34 + y + 1) * 34 + x + 1] = leakyf(acc[j]);
}

// ---------- dt2: ConvT 16->8 K4 S2 P1, parity form, COB2 ----------
__global__ __launch_bounds__(256) void dt2p_k(const float* __restrict__ d1p,
                                              const float* __restrict__ dw2,
                                              const float* __restrict__ db2,
                                              float* __restrict__ d2p)
{
    __shared__ float wl[512];
    int t = threadIdx.x;
    int id = blockIdx.x * 256 + t;                 // 262144
    int x = id & 31, y = (id >> 5) & 31;
    int cg = rfl((id >> 10) & 3), n = id >> 12;
    for (int i = t; i < 512; i += 256) {
        int co = i & 1, tap = (i >> 1) & 15, ci = i >> 5;
        wl[i] = dw2[(ci * 8 + cg * 2 + co) * 16 + tap];
    }
    __syncthreads();
    float acc[2][2][2];
    #pragma unroll
    for (int py = 0; py < 2; ++py)
        #pragma unroll
        for (int px = 0; px < 2; ++px)
            #pragma unroll
            for (int j = 0; j < 2; ++j) acc[py][px][j] = db2[cg * 2 + j];
    #pragma unroll 1
    for (int ci = 0; ci < 16; ++ci) {
        const float* base = d1p + ((n * 16 + ci) * 34 + y) * 34 + x;
        F4 r0 = *(const F4*)(base);
        F4 r1 = *(const F4*)(base + 34);
        F4 r2 = *(const F4*)(base + 68);
        float v[3][3] = { { r0.x, r0.y, r0.z },
                          { r1.x, r1.y, r1.z },
                          { r2.x, r2.y, r2.z } };
        #pragma unroll
        for (int ky = 0; ky < 4; ++ky) {
            int py = (ky + 1) & 1;
            int dy = (ky == 0) ? 1 : (ky == 3 ? -1 : 0);
            #pragma unroll
            for (int kx = 0; kx < 4; ++kx) {
                int px = (kx + 1) & 1;
                int dx = (kx == 0) ? 1 : (kx == 3 ? -1 : 0);
                float vv = v[dy + 1][dx + 1];
                const float* wp = &wl[(ci * 16 + ky * 4 + kx) * 2];
                acc[py][px][0] = fmaf(vv, wp[0], acc[py][px][0]);
                acc[py][px][1] = fmaf(vv, wp[1], acc[py][px][1]);
            }
        }
    }
    #pragma unroll
    for (int py = 0; py < 2; ++py)
        #pragma unroll
        for (int px = 0; px < 2; ++px)
            #pragma unroll
            for (int j = 0; j < 2; ++j)
                d2p[((n * 8 + cg * 2 + j) * 66 + 2 * y + py + 1) * 66 + 2 * x + px + 1] =
                    leakyf(acc[py][px][j]);
}

// ---------- dt3: ConvT 8->1 K4 S2 P1, parity form, tanh ----------
__global__ __launch_bounds__(256) void dt3p_k(const float* __restrict__ d2p,
                                              const float* __restrict__ dw3,
                                              const float* __restrict__ db3,
                                              float* __restrict__ out)
{
    int id = blockIdx.x * 256 + threadIdx.x;       // 262144
    int x = id & 63, y = (id >> 6) & 63, n = id >> 12;
    float b = db3[0];
    float acc[2][2] = { { b, b }, { b, b } };
    #pragma unroll 1
    for (int ci = 0; ci < 8; ++ci) {
        const float* base = d2p + ((n * 8 + ci) * 66 + y) * 66 + x;
        F4 r0 = *(const F4*)(base);
        F4 r1 = *(const F4*)(base + 66);
        F4 r2 = *(const F4*)(base + 132);
        float v[3][3] = { { r0.x, r0.y, r0.z },
                          { r1.x, r1.y, r1.z },
                          { r2.x, r2.y, r2.z } };
        #pragma unroll
        for (int ky = 0; ky < 4; ++ky) {
            int py = (ky + 1) & 1;
            int dy = (ky == 0) ? 1 : (ky == 3 ? -1 : 0);
            #pragma unroll
            for (int kx = 0; kx < 4; ++kx) {
                int px = (kx + 1) & 1;
                int dx = (kx == 0) ? 1 : (kx == 3 ? -1 : 0);
                acc[py][px] = fmaf(v[dy + 1][dx + 1], dw3[ci * 16 + ky * 4 + kx],
                                   acc[py][px]);
            }
        }
    }
    #pragma unroll
    for (int py = 0; py < 2; ++py)
        #pragma unroll
        for (int px = 0; px < 2; ++px)
            out[(n << 14) + ((2 * y + py) << 7) + 2 * x + px] = tanhf(acc[py][px]);
}

extern "C" void kernel_launch(void* const* d_in, const int* in_sizes, int n_in,
                              void* d_out, int out_size, void* d_ws, size_t ws_size,
                              hipStream_t stream)
{
    const float* x        = (const float*)d_in[0];
    const float* ew1      = (const float*)d_in[1];
    const float* eb1      = (const float*)d_in[2];
    const float* ew2      = (const float*)d_in[3];
    const float* eb2      = (const float*)d_in[4];
    const float* ew3      = (const float*)d_in[5];
    const float* eb3      = (const float*)d_in[6];
    const float* ew4      = (const float*)d_in[7];
    const float* eb4      = (const float*)d_in[8];
    const float* codebook = (const float*)d_in[9];
    const float* dw1      = (const float*)d_in[10];
    const float* db1      = (const float*)d_in[11];
    const float* dw2      = (const float*)d_in[12];
    const float* db2      = (const float*)d_in[13];
    const float* dw3      = (const float*)d_in[14];
    const float* db3      = (const float*)d_in[15];

    float* out = (float*)d_out;
    float* ws  = (float*)d_ws;
    float* H1P  = ws + OFF_H1P;
    float* H2P  = ws + OFF_H2P;
    float* H3   = ws + OFF_H3;
    float* D1P  = ws + OFF_D1P;
    float* D2P  = ws + OFF_D2P;
    int*   IDX  = (int*)(ws + OFF_IDX);
    float* U    = ws + OFF_U;
    float* C2   = ws + OFF_C2;
    float* W4T  = ws + OFF_W4T;
    float* LOSS = ws + OFF_LOSS;
    float* DWT  = ws + OFF_DWT;

    setup_k<<<2139, 256, 0, stream>>>(ew4, dw1, codebook, ws);
    uprep_k<<<288, 256, 0, stream>>>(DWT, codebook, U);

    e1d_k<<<1024, 256, 0, stream>>>(x, ew1, eb1, H1P);
    e2p_k<<<1024, 256, 0, stream>>>(H1P, ew2, eb2, H2P);
    e3p_k<<<1024, 256, 0, stream>>>(H2P, ew3, eb3, H3);

    vqn_k<<<512, 384, 0, stream>>>(H3, W4T, eb4, codebook, C2, IDX, LOSS);

    d1p_k<<<1024, 256, 0, stream>>>(IDX, U, db1, LOSS, out + 1048576, D1P);
    dt2p_k<<<1024, 256, 0, stream>>>(D1P, dw2, db2, D2P);
    dt3p_k<<<1024, 256, 0, stream>>>(D2P, dw3, db3, out);
}

// Round 19
// 134.636 us; speedup vs baseline: 1.1786x; 1.1786x over previous
//
#include <hip/hip_runtime.h>
#include <math.h>

#define DEV __device__ __forceinline__
DEV float leakyf(float v) { return v >= 0.f ? v : 0.01f * v; }
DEV int rfl(int v) { return __builtin_amdgcn_readfirstlane(v); }

struct F4 { float x, y, z, w; };   // natural align 4: legal on any float*

// ---- ws layout (float offsets) ----
#define OFF_H1P  1081600u    // h1 [64][8][66][66]           2230272
#define OFF_H2P  3311872u    // h2 [64][16][34][34]          1183744
#define OFF_H3   4495616u    // h3 [64][16][32][32]          1048576
#define OFF_D1P  5544192u    // d1 [64][16][34][34]          1183744
#define OFF_D2P  6727936u    // d2 [64][8][66][66]           2230272
#define OFF_IDX  8958208u    // 65536 int32
#define OFF_U    9023744u    // 73728 [k512][tap9][co16]
#define OFF_C2   9097472u    // 512
#define OFF_W4T  9097984u    // 1024 [ci16][d64]
#define OFF_LOSS 9099008u    // 1 (+pad)
#define OFF_DWT  9100032u    // 9216 [ci64][tap9*16+co16]

// ---------- halo zeroing helper ----------
DEV void halo_store(float* base, int plane, int r, int W, int H, long psz)
{
    int row, col;
    if (r < W)          { row = 0;     col = r; }
    else if (r < 2 * W) { row = H - 1; col = r - W; }
    else { int r2 = r - 2 * W; row = 1 + (r2 >> 1); col = (r2 & 1) ? W - 1 : 0; }
    base[plane * psz + row * W + col] = 0.f;
}

// ---------- setup: halos + W4T + C2 + DWT + LOSS zero (no x padding) ----------
__global__ void setup_k(const float* __restrict__ ew4, const float* __restrict__ dw1,
                        const float* __restrict__ cb, float* __restrict__ ws)
{
    int id = blockIdx.x * 256 + threadIdx.x;       // 547456 ids
    if (id < 133120) {                             // H1P halos: 512 x 260
        halo_store(ws + OFF_H1P, id / 260, id % 260, 66, 66, 4356);
    } else if (id < 268288) {                      // H2P halos: 1024 x 132
        int i = id - 133120;
        halo_store(ws + OFF_H2P, i / 132, i % 132, 34, 34, 1156);
    } else if (id < 403456) {                      // D1P halos
        int i = id - 268288;
        halo_store(ws + OFF_D1P, i / 132, i % 132, 34, 34, 1156);
    } else if (id < 536576) {                      // D2P halos: 512 x 260
        int i = id - 403456;
        halo_store(ws + OFF_D2P, i / 260, i % 260, 66, 66, 4356);
    } else if (id < 537600) {                      // W4T: [ci*64+d] = ew4[d][ci]
        int i = id - 536576;
        int d = i & 63, ci = i >> 6;
        ws[OFF_W4T + i] = ew4[d * 16 + ci];
    } else if (id < 538112) {                      // C2
        int k = id - 537600;
        float s = 0.f;
        #pragma unroll
        for (int d = 0; d < 64; ++d) { float v = cb[k * 64 + d]; s = fmaf(v, v, s); }
        ws[OFF_C2 + k] = s;
    } else if (id == 538112) {
        ws[OFF_LOSS] = 0.f;
    } else if (id >= 538240 && id < 547456) {      // DWT: [ci*144+tap*16+co]
        int i = id - 538240;
        int co = i & 15, tap = (i >> 4) % 9, ci = i / 144;
        ws[OFF_DWT + i] = dw1[(co * 64 + ci) * 9 + tap];
    }
}

// U[k][tap][co] = sum_ci dwT[ci][tap*16+co] * cb[k][ci]   (coalesced)
__global__ void uprep_k(const float* __restrict__ dwT, const float* __restrict__ cb,
                        float* __restrict__ U)
{
    int id = blockIdx.x * 256 + threadIdx.x;   // 73728
    int k = id / 144;
    int r = id - k * 144;
    float s = 0.f;
    #pragma unroll
    for (int ci = 0; ci < 64; ++ci)
        s = fmaf(cb[k * 64 + ci], dwT[ci * 144 + r], s);
    U[id] = s;
}

// ---------- e1: 1->8, K4 S2 P1, reads x directly (bounds-checked) ----------
__global__ __launch_bounds__(256) void e1d_k(const float* __restrict__ x,
                                             const float* __restrict__ ew1,
                                             const float* __restrict__ eb1,
                                             float* __restrict__ h1p)
{
    __shared__ float wl[128];
    int t = threadIdx.x;
    if (t < 128) { int co = t & 7, tap = t >> 3; wl[t] = ew1[co * 16 + tap]; }
    __syncthreads();
    int id = blockIdx.x * 256 + t;                 // 262144
    int px = id & 63, py = (id >> 6) & 63, n = id >> 12;
    float acc[8];
    #pragma unroll
    for (int j = 0; j < 8; ++j) acc[j] = eb1[j];
    const float* ip = x + (n << 14);
    #pragma unroll
    for (int ky = 0; ky < 4; ++ky) {
        int iy = 2 * py - 1 + ky;
        bool vy = iy >= 0 && iy < 128;
        #pragma unroll
        for (int kx = 0; kx < 4; ++kx) {
            int ix = 2 * px - 1 + kx;
            float v = (vy && ix >= 0 && ix < 128) ? ip[(iy << 7) + ix] : 0.f;
            const float* wp = &wl[(ky * 4 + kx) * 8];
            #pragma unroll
            for (int j = 0; j < 8; ++j) acc[j] = fmaf(v, wp[j], acc[j]);
        }
    }
    #pragma unroll
    for (int j = 0; j < 8; ++j)
        h1p[((n * 8 + j) * 66 + py + 1) * 66 + px + 1] = leakyf(acc[j]);
}

// ---------- e2: 8->16, K4 S2 P1, COB4 ----------
__global__ __launch_bounds__(256) void e2p_k(const float* __restrict__ h1p,
                                             const float* __restrict__ ew2,
                                             const float* __restrict__ eb2,
                                             float* __restrict__ h2p)
{
    __shared__ float wl[512];
    int t = threadIdx.x;
    int id = blockIdx.x * 256 + t;                 // 262144
    int x = id & 31, y = (id >> 5) & 31;
    int cg = rfl((id >> 10) & 3), n = id >> 12;
    for (int i = t; i < 512; i += 256) {
        int co = i & 3, r = i >> 2;
        int kx = r & 3, ky = (r >> 2) & 3, ci = r >> 4;
        wl[i] = ew2[((cg * 4 + co) * 8 + ci) * 16 + ky * 4 + kx];
    }
    __syncthreads();
    float acc[4];
    #pragma unroll
    for (int j = 0; j < 4; ++j) acc[j] = eb2[cg * 4 + j];
    #pragma unroll 1
    for (int ci = 0; ci < 8; ++ci) {
        const float* base = h1p + ((n * 8 + ci) * 66 + 2 * y) * 66 + 2 * x;
        #pragma unroll
        for (int ky = 0; ky < 4; ++ky) {
            F4 v = *(const F4*)(base + ky * 66);
            float vv[4] = { v.x, v.y, v.z, v.w };
            #pragma unroll
            for (int kx = 0; kx < 4; ++kx) {
                const float* wp = &wl[((ci * 4 + ky) * 4 + kx) * 4];
                acc[0] = fmaf(vv[kx], wp[0], acc[0]);
                acc[1] = fmaf(vv[kx], wp[1], acc[1]);
                acc[2] = fmaf(vv[kx], wp[2], acc[2]);
                acc[3] = fmaf(vv[kx], wp[3], acc[3]);
            }
        }
    }
    #pragma unroll
    for (int j = 0; j < 4; ++j)
        h2p[((n * 16 + cg * 4 + j) * 34 + y + 1) * 34 + x + 1] = leakyf(acc[j]);
}

// ---------- e3: 16->16, K3 S1 P1, COB4; writes UNPADDED h3 ----------
__global__ __launch_bounds__(256) void e3p_k(const float* __restrict__ h2p,
                                             const float* __restrict__ ew3,
                                             const float* __restrict__ eb3,
                                             float* __restrict__ h3)
{
    __shared__ float wl[576];
    int t = threadIdx.x;
    int id = blockIdx.x * 256 + t;                 // 262144
    int x = id & 31, y = (id >> 5) & 31;
    int cg = rfl((id >> 10) & 3), n = id >> 12;
    for (int i = t; i < 576; i += 256) {
        int co = i & 3, r = i >> 2;
        int kx = r % 3, ky = (r / 3) % 3, ci = r / 9;
        wl[i] = ew3[((cg * 4 + co) * 16 + ci) * 9 + ky * 3 + kx];
    }
    __syncthreads();
    float acc[4];
    #pragma unroll
    for (int j = 0; j < 4; ++j) acc[j] = eb3[cg * 4 + j];
    #pragma unroll 1
    for (int ci = 0; ci < 16; ++ci) {
        const float* base = h2p + ((n * 16 + ci) * 34 + y) * 34 + x;
        #pragma unroll
        for (int ky = 0; ky < 3; ++ky) {
            F4 v = *(const F4*)(base + ky * 34);
            float vv[3] = { v.x, v.y, v.z };
            #pragma unroll
            for (int kx = 0; kx < 3; ++kx) {
                const float* wp = &wl[((ci * 3 + ky) * 3 + kx) * 4];
                acc[0] = fmaf(vv[kx], wp[0], acc[0]);
                acc[1] = fmaf(vv[kx], wp[1], acc[1]);
                acc[2] = fmaf(vv[kx], wp[2], acc[2]);
                acc[3] = fmaf(vv[kx], wp[3], acc[3]);
            }
        }
    }
    #pragma unroll
    for (int j = 0; j < 4; ++j)
        h3[((n * 16 + cg * 4 + j) << 10) + (y << 5) + x] = leakyf(acc[j]);
}

// ---------- fused e4 + VQ, d-major LDS GEMM (r9/r14/r17-proven: 76 us) ----------
__global__ __launch_bounds__(256) void vqh_k(const float* __restrict__ h3,
                                             const float* __restrict__ w4t,
                                             const float* __restrict__ eb4,
                                             const float* __restrict__ cb,
                                             const float* __restrict__ c2,
                                             int* __restrict__ idxOut,
                                             float* __restrict__ lossAcc)
{
    __shared__ float Fs[64 * 128];
    __shared__ float Cs[64 * 128];
    int t = threadIdx.x;
    int row0 = blockIdx.x << 7;
    int n = row0 >> 10;
    int pos0 = row0 & 1023;

    {
        int row = t & 127, dh = t >> 7;
        const float* hp = h3 + (n << 14) + pos0 + row;
        float h[16];
        #pragma unroll
        for (int ci = 0; ci < 16; ++ci) h[ci] = hp[ci << 10];
        #pragma unroll
        for (int q = 0; q < 8; ++q) {
            int d0 = dh * 32 + q * 4;
            float a0 = eb4[d0 + 0], a1 = eb4[d0 + 1];
            float a2 = eb4[d0 + 2], a3 = eb4[d0 + 3];
            #pragma unroll
            for (int ci = 0; ci < 16; ++ci) {
                float v = h[ci];
                const float* wp = w4t + (ci << 6) + d0;
                a0 = fmaf(v, wp[0], a0); a1 = fmaf(v, wp[1], a1);
                a2 = fmaf(v, wp[2], a2); a3 = fmaf(v, wp[3], a3);
            }
            Fs[(d0 + 0) * 128 + row] = leakyf(a0);
            Fs[(d0 + 1) * 128 + row] = leakyf(a1);
            Fs[(d0 + 2) * 128 + row] = leakyf(a2);
            Fs[(d0 + 3) * 128 + row] = leakyf(a3);
        }
    }

    int tr = t & 15, tc = t >> 4;
    float best[8]; int bk[8];
    #pragma unroll
    for (int i = 0; i < 8; ++i) { best[i] = 3.4e38f; bk[i] = 0; }

    #pragma unroll 1
    for (int p = 0; p < 4; ++p) {
        __syncthreads();
        {
            int code = t >> 1, dh = t & 1;
            const float* src = cb + (((p << 7) + code) << 6) + dh * 32;
            #pragma unroll
            for (int q = 0; q < 8; ++q) {
                float4 v = *(const float4*)(src + q * 4);
                int d0 = dh * 32 + q * 4;
                Cs[(d0 + 0) * 128 + code] = v.x;
                Cs[(d0 + 1) * 128 + code] = v.y;
                Cs[(d0 + 2) * 128 + code] = v.z;
                Cs[(d0 + 3) * 128 + code] = v.w;
            }
        }
        __syncthreads();

        float acc[8][8];
        #pragma unroll
        for (int i = 0; i < 8; ++i)
            #pragma unroll
            for (int j = 0; j < 8; ++j) acc[i][j] = 0.f;

        const float* fp0 = &Fs[tr * 4];
        const float* fp1 = &Fs[64 + tr * 4];
        const float* cp0 = &Cs[tc * 4];
        const float* cp1 = &Cs[64 + tc * 4];
        #pragma unroll 8
        for (int d = 0; d < 64; ++d) {
            float4 f0 = *(const float4*)(fp0 + d * 128);
            float4 f1 = *(const float4*)(fp1 + d * 128);
            float4 c0 = *(const float4*)(cp0 + d * 128);
            float4 c1 = *(const float4*)(cp1 + d * 128);
            float f[8] = { f0.x, f0.y, f0.z, f0.w, f1.x, f1.y, f1.z, f1.w };
            float c[8] = { c0.x, c0.y, c0.z, c0.w, c1.x, c1.y, c1.z, c1.w };
            #pragma unroll
            for (int i = 0; i < 8; ++i)
                #pragma unroll
                for (int j = 0; j < 8; ++j)
                    acc[i][j] = fmaf(f[i], c[j], acc[i][j]);
        }
        #pragma unroll
        for (int j = 0; j < 8; ++j) {
            int kk = (p << 7) + (j < 4 ? tc * 4 + j : 64 + tc * 4 + j - 4);
            float hc2 = 0.5f * c2[kk];
            #pragma unroll
            for (int i = 0; i < 8; ++i) {
                float s = hc2 - acc[i][j];
                if (s < best[i]) { best[i] = s; bk[i] = kk; }
            }
        }
    }

    __syncthreads();
    float* redS = Cs;
    int*   redI = (int*)(Cs + 2176);
    #pragma unroll
    for (int i = 0; i < 8; ++i) {
        int row = (i < 4) ? tr * 4 + i : 64 + tr * 4 + i - 4;
        redS[row * 17 + tc] = best[i];
        redI[row * 17 + tc] = bk[i];
    }
    __syncthreads();
    if (t < 128) {
        int row = t;
        float bs = redS[row * 17]; int bi = redI[row * 17];
        #pragma unroll
        for (int c = 1; c < 16; ++c) {
            float s2 = redS[row * 17 + c];
            int   i2 = redI[row * 17 + c];
            if (s2 < bs || (s2 == bs && i2 < bi)) { bs = s2; bi = i2; }
        }
        idxOut[row0 + row] = bi;
        const float* cr = cb + (bi << 6);
        float rs = 0.f;
        #pragma unroll
        for (int d = 0; d < 64; ++d) {
            float e = cr[d] - Fs[d * 128 + row];
            rs = fmaf(e, e, rs);
        }
        #pragma unroll
        for (int off = 32; off; off >>= 1) rs += __shfl_down(rs, off, 64);
        if ((t & 63) == 0) atomicAdd(lossAcc, rs);
    }
}

// ---------- d1 via U-table, writes PADDED D1P; finalizes loss ----------
__global__ __launch_bounds__(256) void d1p_k(const int* __restrict__ idx,
                                             const float* __restrict__ U,
                                             const float* __restrict__ db1,
                                             const float* __restrict__ lossAcc,
                                             float* __restrict__ lossOut,
                                             float* __restrict__ d1p)
{
    int id = blockIdx.x * 256 + threadIdx.x;       // 262144
    if (id == 0) lossOut[0] = 1.25f * lossAcc[0] / 4194304.0f;
    int x = id & 31, y = (id >> 5) & 31;
    int cg = rfl((id >> 10) & 3), n = id >> 12;
    float acc[4];
    #pragma unroll
    for (int j = 0; j < 4; ++j) acc[j] = db1[cg * 4 + j];
    const float4* U4 = (const float4*)U;
    #pragma unroll
    for (int tap = 0; tap < 9; ++tap) {
        int yy = y + tap / 3 - 1, xx = x + tap % 3 - 1;
        if (yy < 0 || yy > 31 || xx < 0 || xx > 31) continue;
        int k = idx[(n << 10) + (yy << 5) + xx];
        float4 u = U4[(k * 9 + tap) * 4 + cg];
        acc[0] += u.x; acc[1] += u.y; acc[2] += u.z; acc[3] += u.w;
    }
    #pragma unroll
    for (int j = 0; j < 4; ++j)
        d1p[((n * 16 + cg * 4 + j) * 34 + y + 1) * 34 + x + 1] = leakyf(acc[j]);
}

// ---------- dt2: ConvT 16->8 K4 S2 P1, parity form, COB2 ----------
__global__ __launch_bounds__(256) void dt2p_k(const float* __restrict__ d1p,
                                              const float* __restrict__ dw2,
                                              const float* __restrict__ db2,
                                              float* __restrict__ d2p)
{
    __shared__ float wl[512];
    int t = threadIdx.x;
    int id = blockIdx.x * 256 + t;                 // 262144
    int x = id & 31, y = (id >> 5) & 31;
    int cg = rfl((id >> 10) & 3), n = id >> 12;
    for (int i = t; i < 512; i += 256) {
        int co = i & 1, tap = (i >> 1) & 15, ci = i >> 5;
        wl[i] = dw2[(ci * 8 + cg * 2 + co) * 16 + tap];
    }
    __syncthreads();
    float acc[2][2][2];
    #pragma unroll
    for (int py = 0; py < 2; ++py)
        #pragma unroll
        for (int px = 0; px < 2; ++px)
            #pragma unroll
            for (int j = 0; j < 2; ++j) acc[py][px][j] = db2[cg * 2 + j];
    #pragma unroll 1
    for (int ci = 0; ci < 16; ++ci) {
        const float* base = d1p + ((n * 16 + ci) * 34 + y) * 34 + x;
        F4 r0 = *(const F4*)(base);
        F4 r1 = *(const F4*)(base + 34);
        F4 r2 = *(const F4*)(base + 68);
        float v[3][3] = { { r0.x, r0.y, r0.z },
                          { r1.x, r1.y, r1.z },
                          { r2.x, r2.y, r2.z } };
        #pragma unroll
        for (int ky = 0; ky < 4; ++ky) {
            int py = (ky + 1) & 1;
            int dy = (ky == 0) ? 1 : (ky == 3 ? -1 : 0);
            #pragma unroll
            for (int kx = 0; kx < 4; ++kx) {
                int px = (kx + 1) & 1;
                int dx = (kx == 0) ? 1 : (kx == 3 ? -1 : 0);
                float vv = v[dy + 1][dx + 1];
                const float* wp = &wl[(ci * 16 + ky * 4 + kx) * 2];
                acc[py][px][0] = fmaf(vv, wp[0], acc[py][px][0]);
                acc[py][px][1] = fmaf(vv, wp[1], acc[py][px][1]);
            }
        }
    }
    #pragma unroll
    for (int py = 0; py < 2; ++py)
        #pragma unroll
        for (int px = 0; px < 2; ++px)
            #pragma unroll
            for (int j = 0; j < 2; ++j)
                d2p[((n * 8 + cg * 2 + j) * 66 + 2 * y + py + 1) * 66 + 2 * x + px + 1] =
                    leakyf(acc[py][px][j]);
}

// ---------- dt3: ConvT 8->1 K4 S2 P1, parity form, tanh ----------
__global__ __launch_bounds__(256) void dt3p_k(const float* __restrict__ d2p,
                                              const float* __restrict__ dw3,
                                              const float* __restrict__ db3,
                                              float* __restrict__ out)
{
    int id = blockIdx.x * 256 + threadIdx.x;       // 262144
    int x = id & 63, y = (id >> 6) & 63, n = id >> 12;
    float b = db3[0];
    float acc[2][2] = { { b, b }, { b, b } };
    #pragma unroll 1
    for (int ci = 0; ci < 8; ++ci) {
        const float* base = d2p + ((n * 8 + ci) * 66 + y) * 66 + x;
        F4 r0 = *(const F4*)(base);
        F4 r1 = *(const F4*)(base + 66);
        F4 r2 = *(const F4*)(base + 132);
        float v[3][3] = { { r0.x, r0.y, r0.z },
                          { r1.x, r1.y, r1.z },
                          { r2.x, r2.y, r2.z } };
        #pragma unroll
        for (int ky = 0; ky < 4; ++ky) {
            int py = (ky + 1) & 1;
            int dy = (ky == 0) ? 1 : (ky == 3 ? -1 : 0);
            #pragma unroll
            for (int kx = 0; kx < 4; ++kx) {
                int px = (kx + 1) & 1;
                int dx = (kx == 0) ? 1 : (kx == 3 ? -1 : 0);
                acc[py][px] = fmaf(v[dy + 1][dx + 1], dw3[ci * 16 + ky * 4 + kx],
                                   acc[py][px]);
            }
        }
    }
    #pragma unroll
    for (int py = 0; py < 2; ++py)
        #pragma unroll
        for (int px = 0; px < 2; ++px)
            out[(n << 14) + ((2 * y + py) << 7) + 2 * x + px] = tanhf(acc[py][px]);
}

extern "C" void kernel_launch(void* const* d_in, const int* in_sizes, int n_in,
                              void* d_out, int out_size, void* d_ws, size_t ws_size,
                              hipStream_t stream)
{
    const float* x        = (const float*)d_in[0];
    const float* ew1      = (const float*)d_in[1];
    const float* eb1      = (const float*)d_in[2];
    const float* ew2      = (const float*)d_in[3];
    const float* eb2      = (const float*)d_in[4];
    const float* ew3      = (const float*)d_in[5];
    const float* eb3      = (const float*)d_in[6];
    const float* ew4      = (const float*)d_in[7];
    const float* eb4      = (const float*)d_in[8];
    const float* codebook = (const float*)d_in[9];
    const float* dw1      = (const float*)d_in[10];
    const float* db1      = (const float*)d_in[11];
    const float* dw2      = (const float*)d_in[12];
    const float* db2      = (const float*)d_in[13];
    const float* dw3      = (const float*)d_in[14];
    const float* db3      = (const float*)d_in[15];

    float* out = (float*)d_out;
    float* ws  = (float*)d_ws;
    float* H1P  = ws + OFF_H1P;
    float* H2P  = ws + OFF_H2P;
    float* H3   = ws + OFF_H3;
    float* D1P  = ws + OFF_D1P;
    float* D2P  = ws + OFF_D2P;
    int*   IDX  = (int*)(ws + OFF_IDX);
    float* U    = ws + OFF_U;
    float* C2   = ws + OFF_C2;
    float* W4T  = ws + OFF_W4T;
    float* LOSS = ws + OFF_LOSS;
    float* DWT  = ws + OFF_DWT;

    setup_k<<<2139, 256, 0, stream>>>(ew4, dw1, codebook, ws);
    uprep_k<<<288, 256, 0, stream>>>(DWT, codebook, U);

    e1d_k<<<1024, 256, 0, stream>>>(x, ew1, eb1, H1P);
    e2p_k<<<1024, 256, 0, stream>>>(H1P, ew2, eb2, H2P);
    e3p_k<<<1024, 256, 0, stream>>>(H2P, ew3, eb3, H3);

    vqh_k<<<512, 256, 0, stream>>>(H3, W4T, eb4, codebook, C2, IDX, LOSS);

    d1p_k<<<1024, 256, 0, stream>>>(IDX, U, db1, LOSS, out + 1048576, D1P);
    dt2p_k<<<1024, 256, 0, stream>>>(D1P, dw2, db2, D2P);
    dt3p_k<<<1024, 256, 0, stream>>>(D2P, dw3, db3, out);
}